// Round 1
// baseline (48.481 us; speedup 1.0000x reference)
//
#include <hip/hip_runtime.h>

#define NN 1024
#define HID 256
#define XD 128

// ws float offsets
#define OFF_PXT   0          // 1024*256 floats, tiled [jblk][kq][j&63][kl]
#define OFF_PYT   262144     // 1024*256
#define OFF_C     524288     // 1024 : c[j] = exp(b2 - ls[j])
#define OFF_PART  525312     // 256  : per-block exp-sum partials
#define OFF_T0P   525568     // 128  : per-prep-block T0 partials (incl +b2 per row)
#define OFF_LSP   525696     // 128  : per-prep-block ls partials

__global__ __launch_bounds__(256) void prep_kernel(
    const float* __restrict__ x, const float* __restrict__ y,
    const float* __restrict__ W1, const float* __restrict__ b1,
    const float* __restrict__ w2, const float* __restrict__ b2p,
    const float* __restrict__ wb, const float* __restrict__ bbp,
    float* __restrict__ ws)
{
  __shared__ float sx[8][128];
  __shared__ float sy[8][128];
  __shared__ float st0[4][8];
  __shared__ float sls[8];
  const int t = threadIdx.x;
  const int blk = blockIdx.x;
  const int r0 = blk * 8;

  {
    const int rl = t >> 5, f = t & 31;
    float4 vx = *(const float4*)(x + (r0 + rl) * XD + f * 4);
    float4 vy = *(const float4*)(y + (r0 + rl) * XD + f * 4);
    *(float4*)&sx[rl][f * 4] = vx;
    *(float4*)&sy[rl][f * 4] = vy;
  }
  __syncthreads();

  const int k = t;  // one hidden unit per thread
  float apx[8] = {0,0,0,0,0,0,0,0};
  float apy[8] = {0,0,0,0,0,0,0,0};
  const float* wrow = W1 + k * 256;
  for (int dq = 0; dq < 32; ++dq) {
    float4 wx = *(const float4*)(wrow + dq * 4);
    float4 wy = *(const float4*)(wrow + 128 + dq * 4);
#pragma unroll
    for (int r = 0; r < 8; ++r) {
      float4 xv = *(const float4*)&sx[r][dq * 4];
      float4 yv = *(const float4*)&sy[r][dq * 4];
      apx[r] = fmaf(xv.x, wx.x, apx[r]);
      apx[r] = fmaf(xv.y, wx.y, apx[r]);
      apx[r] = fmaf(xv.z, wx.z, apx[r]);
      apx[r] = fmaf(xv.w, wx.w, apx[r]);
      apy[r] = fmaf(yv.x, wy.x, apy[r]);
      apy[r] = fmaf(yv.y, wy.y, apy[r]);
      apy[r] = fmaf(yv.z, wy.z, apy[r]);
      apy[r] = fmaf(yv.w, wy.w, apy[r]);
    }
  }
  const float b1k = b1[k];
#pragma unroll
  for (int r = 0; r < 8; ++r) apy[r] += b1k;  // fold b1 into py

  // write tiled layouts: [blk64][kq][slot64][kl4]
  {
    const int kq = k >> 2, kl = k & 3;
    float* pxt = ws + OFF_PXT;
    float* pyt = ws + OFF_PYT;
#pragma unroll
    for (int r = 0; r < 8; ++r) {
      const int j = r0 + r;
      const int idx = (j >> 6) * 16384 + kq * 256 + (j & 63) * 4 + kl;
      pxt[idx] = apx[r];
      pyt[idx] = apy[r];
    }
  }

  // T0 partials: T0[r] = sum_k relu(px+pyb)*w2 + b2
  const float w2k = w2[k];
  const float b2v = b2p[0];
  const int wv = t >> 6, lane = t & 63;
#pragma unroll
  for (int r = 0; r < 8; ++r) {
    float v = fmaxf(apx[r] + apy[r], 0.f) * w2k;
    for (int o = 32; o > 0; o >>= 1) v += __shfl_down(v, o);
    if (lane == 0) st0[wv][r] = v;
  }

  // ls[r] = y[r] . wb + bb ; c[r] = exp(b2 - ls[r])
  {
    const int rl = t >> 5, f = t & 31;
    float p = 0.f;
#pragma unroll
    for (int l = 0; l < 4; ++l) p = fmaf(sy[rl][f * 4 + l], wb[f * 4 + l], p);
    for (int m = 16; m > 0; m >>= 1) p += __shfl_xor(p, m);
    if (f == 0) {
      const float lsv = p + bbp[0];
      sls[rl] = lsv;
      ws[OFF_C + r0 + rl] = __expf(b2v - lsv);
    }
  }
  __syncthreads();
  if (t == 0) {
    float t0s = 0.f, lss = 0.f;
#pragma unroll
    for (int r = 0; r < 8; ++r) {
      t0s += st0[0][r] + st0[1][r] + st0[2][r] + st0[3][r] + b2v;
      lss += sls[r];
    }
    ws[OFF_T0P + blk] = t0s;
    ws[OFF_LSP + blk] = lss;
  }
}

__global__ __launch_bounds__(256) void main_kernel(
    float* __restrict__ ws, const float* __restrict__ w2)
{
  __shared__ float spx[4096];  // [16 kq][64 slot][4 kl]
  __shared__ float spy[4096];
  __shared__ float sw2[256];
  __shared__ float sred[4];
  const int t = threadIdx.x;
  const int tx = t & 15, ty = t >> 4;
  const int blk = blockIdx.x;
  const int bi = blk >> 4, bj = blk & 15;
  const float* pxt = ws + OFF_PXT + bj * 16384;
  const float* pyt = ws + OFF_PYT + bi * 16384;
  sw2[t] = w2[t];
  float acc[4][4] = {{0.f,0.f,0.f,0.f},{0.f,0.f,0.f,0.f},
                     {0.f,0.f,0.f,0.f},{0.f,0.f,0.f,0.f}};
  for (int c = 0; c < 4; ++c) {
    __syncthreads();  // protect LDS from previous chunk's readers (also covers sw2)
    {
      const float4* gx = (const float4*)(pxt + c * 4096);
      const float4* gy = (const float4*)(pyt + c * 4096);
      float4* lx = (float4*)spx;
      float4* ly = (float4*)spy;
#pragma unroll
      for (int it = 0; it < 4; ++it) {
        lx[it * 256 + t] = gx[it * 256 + t];
        ly[it * 256 + t] = gy[it * 256 + t];
      }
    }
    __syncthreads();
    const float4* spx4 = (const float4*)spx;
    const float4* spy4 = (const float4*)spy;
    const float4* sw24 = (const float4*)sw2;
    for (int kq = 0; kq < 16; ++kq) {
      const float4 wq = sw24[c * 16 + kq];
      float4 A[4], B[4];
#pragma unroll
      for (int u = 0; u < 4; ++u) {
        A[u] = spx4[kq * 64 + u * 16 + tx];
        B[u] = spy4[kq * 64 + u * 16 + ty];
      }
#pragma unroll
      for (int io = 0; io < 4; ++io) {
        const float4 b = B[io];
#pragma unroll
        for (int jo = 0; jo < 4; ++jo) {
          const float4 a = A[jo];
          float t0 = fmaxf(a.x + b.x, 0.f);
          float t1 = fmaxf(a.y + b.y, 0.f);
          float t2 = fmaxf(a.z + b.z, 0.f);
          float t3 = fmaxf(a.w + b.w, 0.f);
          float s = acc[io][jo];
          s = fmaf(t0, wq.x, s);
          s = fmaf(t1, wq.y, s);
          s = fmaf(t2, wq.z, s);
          s = fmaf(t3, wq.w, s);
          acc[io][jo] = s;
        }
      }
    }
  }
  // epilogue: sum exp(S)*c[j]
  const float* cj = ws + OFF_C + bj * 64;
  const float c0 = cj[tx], c1 = cj[16 + tx], c2 = cj[32 + tx], c3 = cj[48 + tx];
  float ts = 0.f;
#pragma unroll
  for (int io = 0; io < 4; ++io) {
    ts += __expf(acc[io][0]) * c0;
    ts += __expf(acc[io][1]) * c1;
    ts += __expf(acc[io][2]) * c2;
    ts += __expf(acc[io][3]) * c3;
  }
  for (int o = 32; o > 0; o >>= 1) ts += __shfl_down(ts, o);
  if ((t & 63) == 0) sred[t >> 6] = ts;
  __syncthreads();
  if (t == 0) ws[OFF_PART + blk] = sred[0] + sred[1] + sred[2] + sred[3];
}

__global__ __launch_bounds__(256) void fin_kernel(
    const float* __restrict__ ws, float* __restrict__ out)
{
  __shared__ float sr[4][3];
  const int t = threadIdx.x;
  float e = ws[OFF_PART + t];
  float t0 = (t < 128) ? ws[OFF_T0P + t] : 0.f;
  float ls = (t < 128) ? ws[OFF_LSP + t] : 0.f;
  for (int o = 32; o > 0; o >>= 1) {
    e  += __shfl_down(e, o);
    t0 += __shfl_down(t0, o);
    ls += __shfl_down(ls, o);
  }
  if ((t & 63) == 0) {
    sr[t >> 6][0] = e;
    sr[t >> 6][1] = t0;
    sr[t >> 6][2] = ls;
  }
  __syncthreads();
  if (t == 0) {
    const float es  = sr[0][0] + sr[1][0] + sr[2][0] + sr[3][0];
    const float t0s = sr[0][1] + sr[1][1] + sr[2][1] + sr[3][1];
    const float lss = sr[0][2] + sr[1][2] + sr[2][2] + sr[3][2];
    out[0] = 1.0f + t0s * (1.0f / 1024.0f) - lss * (1.0f / 1024.0f)
                  - es * (1.0f / 1048576.0f);
  }
}

extern "C" void kernel_launch(void* const* d_in, const int* in_sizes, int n_in,
                              void* d_out, int out_size, void* d_ws, size_t ws_size,
                              hipStream_t stream) {
  const float* x  = (const float*)d_in[0];
  const float* y  = (const float*)d_in[1];
  const float* W1 = (const float*)d_in[2];
  const float* b1 = (const float*)d_in[3];
  const float* w2 = (const float*)d_in[4];
  const float* b2 = (const float*)d_in[5];
  const float* wb = (const float*)d_in[6];
  const float* bb = (const float*)d_in[7];
  float* ws  = (float*)d_ws;
  float* out = (float*)d_out;

  hipLaunchKernelGGL(prep_kernel, dim3(128), dim3(256), 0, stream,
                     x, y, W1, b1, w2, b2, wb, bb, ws);
  hipLaunchKernelGGL(main_kernel, dim3(256), dim3(256), 0, stream, ws, w2);
  hipLaunchKernelGGL(fin_kernel, dim3(1), dim3(256), 0, stream, ws, out);
}

// Round 2
// 33.876 us; speedup vs baseline: 1.4311x; 1.4311x over previous
//
#include <hip/hip_runtime.h>
#include <hip/hip_fp16.h>

#define NN 1024
#define HID 256
#define XD 128

typedef _Float16 h2 __attribute__((ext_vector_type(2)));

// ws layout:
//   halfs:  pxh [0, 262144)   tiled [jblk16][ko32][slot64][kl8]
//           pyh [262144, 524288)
//           w2h [524288, 524544)
//   floats at byte 1049600 (wsf):
//           C    [0,1024)      c[j] = exp(b2 - ls[j])
//           PART [1024,3072)   per-wave exp-sum partials (256 blk x 8 waves)
//           T0P  [3072,3328)   per-prep-block T0 partials
//           LSP  [3328,3584)   per-prep-block ls partials
#define WSF_BYTE_OFF 1049600
#define F_C    0
#define F_PART 1024
#define F_T0P  3072
#define F_LSP  3328

__device__ __forceinline__ h2 relu2(h2 x) {
  h2 z = {(_Float16)0, (_Float16)0};
  return __builtin_elementwise_max(x, z);
}

__device__ __forceinline__ float dot2f(h2 a, h2 b, float c) {
#if __has_builtin(__builtin_amdgcn_fdot2)
  return __builtin_amdgcn_fdot2(a, b, c, false);
#else
  return fmaf((float)a.x, (float)b.x, fmaf((float)a.y, (float)b.y, c));
#endif
}

__global__ __launch_bounds__(256) void prep_kernel(
    const float* __restrict__ x, const float* __restrict__ y,
    const float* __restrict__ W1, const float* __restrict__ b1,
    const float* __restrict__ w2, const float* __restrict__ b2p,
    const float* __restrict__ wb, const float* __restrict__ bbp,
    _Float16* __restrict__ wsh, float* __restrict__ wsf)
{
  __shared__ float sx[4][128];
  __shared__ float sy[4][128];
  __shared__ float st0[4][4];
  __shared__ float sls[4];
  const int t = threadIdx.x;
  const int blk = blockIdx.x;
  const int r0 = blk * 4;

  {
    const int rl = (t & 127) >> 5, f = t & 31;
    if (t < 128) {
      *(float4*)&sx[rl][f * 4] = *(const float4*)(x + (r0 + rl) * XD + f * 4);
    } else {
      *(float4*)&sy[rl][f * 4] = *(const float4*)(y + (r0 + rl) * XD + f * 4);
    }
  }
  __syncthreads();

  const int k = t;  // one hidden unit per thread
  float apx[4] = {0,0,0,0};
  float apy[4] = {0,0,0,0};
  const float* wrow = W1 + k * 256;
  for (int dq = 0; dq < 32; ++dq) {
    float4 wx = *(const float4*)(wrow + dq * 4);
    float4 wy = *(const float4*)(wrow + 128 + dq * 4);
#pragma unroll
    for (int r = 0; r < 4; ++r) {
      float4 xv = *(const float4*)&sx[r][dq * 4];
      float4 yv = *(const float4*)&sy[r][dq * 4];
      apx[r] = fmaf(xv.x, wx.x, apx[r]);
      apx[r] = fmaf(xv.y, wx.y, apx[r]);
      apx[r] = fmaf(xv.z, wx.z, apx[r]);
      apx[r] = fmaf(xv.w, wx.w, apx[r]);
      apy[r] = fmaf(yv.x, wy.x, apy[r]);
      apy[r] = fmaf(yv.y, wy.y, apy[r]);
      apy[r] = fmaf(yv.z, wy.z, apy[r]);
      apy[r] = fmaf(yv.w, wy.w, apy[r]);
    }
  }
  const float b1k = b1[k];
#pragma unroll
  for (int r = 0; r < 4; ++r) apy[r] += b1k;  // fold b1 into py

  // write f16 tiled layouts
  {
    const int ko = k >> 3, kl = k & 7;
    _Float16* pxh = wsh;
    _Float16* pyh = wsh + 262144;
#pragma unroll
    for (int r = 0; r < 4; ++r) {
      const int j = r0 + r;
      const int idx = (j >> 6) * 16384 + ko * 512 + (j & 63) * 8 + kl;
      pxh[idx] = (_Float16)apx[r];
      pyh[idx] = (_Float16)apy[r];
    }
  }

  // T0 partials (exact f32)
  const float w2k = w2[k];
  const float b2v = b2p[0];
  const int wv = t >> 6, lane = t & 63;
#pragma unroll
  for (int r = 0; r < 4; ++r) {
    float v = fmaxf(apx[r] + apy[r], 0.f) * w2k;
    for (int o = 32; o > 0; o >>= 1) v += __shfl_down(v, o);
    if (lane == 0) st0[wv][r] = v;
  }

  // ls[r] = y[r].wb + bb ; c[r] = exp(b2 - ls[r])
  if (t < 128) {
    const int rl = t >> 5, f = t & 31;
    float p = 0.f;
#pragma unroll
    for (int l = 0; l < 4; ++l) p = fmaf(sy[rl][f * 4 + l], wb[f * 4 + l], p);
    for (int m = 16; m > 0; m >>= 1) p += __shfl_xor(p, m);
    if (f == 0) {
      const float lsv = p + bbp[0];
      sls[rl] = lsv;
      wsf[F_C + r0 + rl] = __expf(b2v - lsv);
    }
  }
  __syncthreads();
  if (t == 0) {
    float t0s = 0.f, lss = 0.f;
#pragma unroll
    for (int r = 0; r < 4; ++r) {
      t0s += st0[0][r] + st0[1][r] + st0[2][r] + st0[3][r] + b2v;
      lss += sls[r];
    }
    wsf[F_T0P + blk] = t0s;
    wsf[F_LSP + blk] = lss;
  }
  // w2 as f16 pairs (block 0 only)
  if (blk == 0 && t < 128) {
    h2* w2h = (h2*)(wsh + 524288);
    h2 w; w.x = (_Float16)w2[2 * t]; w.y = (_Float16)w2[2 * t + 1];
    w2h[t] = w;
  }
}

__global__ __launch_bounds__(512) void main_kernel(
    const _Float16* __restrict__ wsh, float* __restrict__ wsf)
{
  __shared__ _Float16 spx[16384];  // [ko32][slot64][kl8] = 32KB
  __shared__ _Float16 spy[16384];
  const int t = threadIdx.x;
  const int tx = t & 15;        // A col group: cols u*16+tx
  const int ty = t >> 4;        // 0..31, B rows v*32+ty
  const int blk = blockIdx.x;
  const int bi = blk >> 4, bj = blk & 15;

  const float4* gx = (const float4*)(wsh + bj * 16384);
  const float4* gy = (const float4*)(wsh + 262144 + bi * 16384);
  const float4* gw = (const float4*)(wsh + 524288);
  float4* lx = (float4*)spx;
  float4* ly = (float4*)spy;
#pragma unroll
  for (int it = 0; it < 4; ++it) {
    lx[it * 512 + t] = gx[it * 512 + t];
    ly[it * 512 + t] = gy[it * 512 + t];
  }
  __syncthreads();

  float acc[2][4] = {{0.f,0.f,0.f,0.f},{0.f,0.f,0.f,0.f}};
  const float4* spx4 = (const float4*)spx;
  const float4* spy4 = (const float4*)spy;

#pragma unroll 2
  for (int ko = 0; ko < 32; ++ko) {
    float4 wv = gw[ko];                  // 4 h2 = 8 w2 values (uniform, cached)
    float4 Af[4], Bf[2];
#pragma unroll
    for (int u = 0; u < 4; ++u) Af[u] = spx4[ko * 64 + u * 16 + tx];
#pragma unroll
    for (int v = 0; v < 2; ++v) Bf[v] = spy4[ko * 64 + v * 32 + ty];
    const h2* wq = (const h2*)&wv;
#pragma unroll
    for (int v = 0; v < 2; ++v) {
      const h2* bh = (const h2*)&Bf[v];
#pragma unroll
      for (int u = 0; u < 4; ++u) {
        const h2* ah = (const h2*)&Af[u];
        float s = acc[v][u];
#pragma unroll
        for (int p = 0; p < 4; ++p) {
          h2 uu = ah[p] + bh[p];         // v_pk_add_f16
          uu = relu2(uu);                // v_pk_max_f16
          s = dot2f(uu, wq[p], s);       // v_dot2_f32_f16
        }
        acc[v][u] = s;
      }
    }
  }

  // epilogue: sum exp(S)*c[j]
  const float* cj = wsf + F_C + bj * 64;
  const float c0 = cj[tx], c1 = cj[16 + tx], c2 = cj[32 + tx], c3 = cj[48 + tx];
  float ts = 0.f;
#pragma unroll
  for (int v = 0; v < 2; ++v) {
    ts += __expf(acc[v][0]) * c0;
    ts += __expf(acc[v][1]) * c1;
    ts += __expf(acc[v][2]) * c2;
    ts += __expf(acc[v][3]) * c3;
  }
  for (int o = 32; o > 0; o >>= 1) ts += __shfl_down(ts, o);
  if ((t & 63) == 0) wsf[F_PART + blk * 8 + (t >> 6)] = ts;
}

__global__ __launch_bounds__(256) void fin_kernel(
    const float* __restrict__ wsf, float* __restrict__ out)
{
  __shared__ float sr[4][3];
  const int t = threadIdx.x;
  float e = 0.f;
#pragma unroll
  for (int q = 0; q < 8; ++q) e += wsf[F_PART + t + 256 * q];
  float t0 = wsf[F_T0P + t];
  float ls = wsf[F_LSP + t];
  for (int o = 32; o > 0; o >>= 1) {
    e  += __shfl_down(e, o);
    t0 += __shfl_down(t0, o);
    ls += __shfl_down(ls, o);
  }
  if ((t & 63) == 0) {
    sr[t >> 6][0] = e;
    sr[t >> 6][1] = t0;
    sr[t >> 6][2] = ls;
  }
  __syncthreads();
  if (t == 0) {
    const float es  = sr[0][0] + sr[1][0] + sr[2][0] + sr[3][0];
    const float t0s = sr[0][1] + sr[1][1] + sr[2][1] + sr[3][1];
    const float lss = sr[0][2] + sr[1][2] + sr[2][2] + sr[3][2];
    out[0] = 1.0f + t0s * (1.0f / 1024.0f) - lss * (1.0f / 1024.0f)
                  - es * (1.0f / 1048576.0f);
  }
}

extern "C" void kernel_launch(void* const* d_in, const int* in_sizes, int n_in,
                              void* d_out, int out_size, void* d_ws, size_t ws_size,
                              hipStream_t stream) {
  const float* x  = (const float*)d_in[0];
  const float* y  = (const float*)d_in[1];
  const float* W1 = (const float*)d_in[2];
  const float* b1 = (const float*)d_in[3];
  const float* w2 = (const float*)d_in[4];
  const float* b2 = (const float*)d_in[5];
  const float* wb = (const float*)d_in[6];
  const float* bb = (const float*)d_in[7];
  _Float16* wsh = (_Float16*)d_ws;
  float* wsf = (float*)((char*)d_ws + WSF_BYTE_OFF);
  float* out = (float*)d_out;

  hipLaunchKernelGGL(prep_kernel, dim3(256), dim3(256), 0, stream,
                     x, y, W1, b1, w2, b2, wb, bb, wsh, wsf);
  hipLaunchKernelGGL(main_kernel, dim3(256), dim3(512), 0, stream, wsh, wsf);
  hipLaunchKernelGGL(fin_kernel, dim3(1), dim3(256), 0, stream, wsf, out);
}